// Round 16
// baseline (46.730 us; speedup 1.0000x reference)
//
#include <hip/hip_runtime.h>
#include <hip/hip_fp16.h>

#define DX 160
#define DY 192
#define DZ 160
#define PLANE (DY*DZ)
#define NVOX (DX*DY*DZ)

#define XC   10               // interior x slices per wave
#define NXB  (DX/XC)          // 16
#define NS   (XC+4)           // 14
#define WPB  4                // waves (= y rows) per block
#define NT   (WPB*64)         // 256 threads
#define NYB  (DY/WPB)         // 48
#define NPART (NXB*NYB*WPB)   // 3072 per-wave partials

__device__ __forceinline__ int iclamp(int v, int hi) {
    return v < 0 ? 0 : (v > hi ? hi : v);
}
__device__ __forceinline__ unsigned pk(float a, float b) {
    return __builtin_bit_cast(unsigned, __floats2half2_rn(a, b));
}
__device__ __forceinline__ float lo16(unsigned u) {
    return __low2float(__builtin_bit_cast(__half2, u));
}
__device__ __forceinline__ float hi16(unsigned u) {
    return __high2float(__builtin_bit_cast(__half2, u));
}

// ---------------------------------------------------------------------------
// Wave-autonomous fused LCC: ZERO LDS, ZERO barriers in the main loop.
// R5-R13 invariants: all pipes <25%, occupancy pinned ~25%, time ~ slice
// count, for EVERY barrier/grid/pipeline variant -> the block-wide barrier +
// cross-wave LDS handoff is itself the serializer. This kernel removes it:
//   - wave = one y row; lane owns z-triple (3l..3l+2), 54 lanes cover z.
//   - y-box: 5 tap rows straight from global (float4; L1 serves 5x reuse).
//   - z-box: fp16-packed neighbor exchange via 2 shuffles/quantity (wave-
//     local ds_bpermute, no sync). Edge clamps: lane0 override; lane>=53
//     duplicates its z=159 value so lane52's right taps clamp for free.
//   - x-box: proven register running window (fp16 history).
//   - reduction: wave shuffle; one partial per wave.
// 3072 independent waves (12/CU), VGPR-capped 128 -> 16 waves/CU resident.
// ---------------------------------------------------------------------------
__global__ __launch_bounds__(NT, 4) void lcc_fused(const float* __restrict__ F,
                                                   const float* __restrict__ M,
                                                   float* __restrict__ partials) {
    const int tid  = threadIdx.x;
    const int lane = tid & 63;
    const int wid  = tid >> 6;
    const int y    = blockIdx.y * WPB + wid;
    const int x0   = blockIdx.x * XC;

    // z-triple base; cap at 156 so the float4 read never leaves the row
    const int  z3   = 3 * lane;
    const int  zoff = z3 < DZ - 4 ? z3 : DZ - 4;   // <=156
    const bool hiL  = (z3 > DZ - 4);               // lanes >= 53: use v.w (z=159)

    // validity masks for the 3 z-slots
    const float mz0 = (z3 + 0 < DZ) ? 1.f : 0.f;
    const float mz1 = (z3 + 1 < DZ) ? 1.f : 0.f;
    const float mz2 = (z3 + 2 < DZ) ? 1.f : 0.f;

    int rowoff[5];
    #pragma unroll
    for (int k = 0; k < 5; ++k)
        rowoff[k] = iclamp(y + k - 2, DY - 1) * DZ + zoff;

    // x running-window state
    float    s[5][3];
    unsigned h01[4][5];   // history: fp16x2 (S[q][0], S[q][1]) per age
    float    h2v[4][5];   // history: S[q][2] (f32)
    #pragma unroll
    for (int q = 0; q < 5; ++q) { s[q][0] = 0.f; s[q][1] = 0.f; s[q][2] = 0.f; }
    #pragma unroll
    for (int a = 0; a < 4; ++a)
        #pragma unroll
        for (int q = 0; q < 5; ++q) { h01[a][q] = 0u; h2v[a][q] = 0.f; }

    float acc = 0.f;

    #pragma unroll
    for (int i = 0; i < NS; ++i) {
        const int xx = iclamp(x0 + i - 2, DX - 1);
        const float* fp = F + (size_t)xx * PLANE;
        const float* mp = M + (size_t)xx * PLANE;

        // ---- y-box over 5 tap rows, straight from global (f32 exact) ----
        float q0[5] = {0,0,0,0,0};   // quantities at z-slot 0: f,m,fm,ff,mm
        float q1[5] = {0,0,0,0,0};   // z-slot 1
        float q2[5] = {0,0,0,0,0};   // z-slot 2
        #pragma unroll
        for (int r = 0; r < 5; ++r) {
            const float4 vf = *(const float4*)(fp + rowoff[r]);
            const float4 vm = *(const float4*)(mp + rowoff[r]);
            const float f0 = hiL ? vf.w : vf.x, m0 = hiL ? vm.w : vm.x;
            const float f1 = hiL ? vf.w : vf.y, m1 = hiL ? vm.w : vm.y;
            const float f2 = hiL ? vf.w : vf.z, m2 = hiL ? vm.w : vm.z;
            q0[0] += f0; q0[1] += m0;
            q0[2] = fmaf(f0, m0, q0[2]); q0[3] = fmaf(f0, f0, q0[3]); q0[4] = fmaf(m0, m0, q0[4]);
            q1[0] += f1; q1[1] += m1;
            q1[2] = fmaf(f1, m1, q1[2]); q1[3] = fmaf(f1, f1, q1[3]); q1[4] = fmaf(m1, m1, q1[4]);
            q2[0] += f2; q2[1] += m2;
            q2[2] = fmaf(f2, m2, q2[2]); q2[3] = fmaf(f2, f2, q2[3]); q2[4] = fmaf(m2, m2, q2[4]);
        }

        // ---- z-box via wave-local shuffles (fp16 neighbor taps) ----
        float S[5][3];
        #pragma unroll
        for (int q = 0; q < 5; ++q) {
            const unsigned up = pk(q1[q], q2[q]);   // my (z1,z2) -> right neighbor
            const unsigned dn = pk(q0[q], q1[q]);   // my (z0,z1) -> left neighbor
            unsigned fl = __shfl_up(up, 1, 64);     // lane-1's (z1,z2) = my z0-2, z0-1
            unsigned fr = __shfl_down(dn, 1, 64);   // lane+1's (z0,z1) = my z2+1, z2+2
            if (lane == 0) fl = pk(q0[q], q0[q]);   // replicate pad at z=0
            // (right edge: lane>=53 duplicated z159 into q1/q2, so lane52's
            //  fr.hi == clamp(z=160) automatically; lane53 uses only S[.][0].)
            const float c = q0[q] + q1[q] + q2[q];
            S[q][0] = c + lo16(fl) + hi16(fl);
            S[q][1] = c + hi16(fl) + lo16(fr);
            S[q][2] = c + lo16(fr) + hi16(fr);
        }

        // ---- x running window + LCC ----
        #pragma unroll
        for (int q = 0; q < 5; ++q) {
            s[q][0] += S[q][0]; s[q][1] += S[q][1]; s[q][2] += S[q][2];
        }
        if (i >= 4) {
            const float inv = 1.0f / 125.0f;
            const float mz[3] = {mz0, mz1, mz2};
            #pragma unroll
            for (int j = 0; j < 3; ++j) {
                const float cross = s[2][j] - s[0][j] * s[1][j] * inv;
                const float fvar  = s[3][j] - s[0][j] * s[0][j] * inv;
                const float mvar  = s[4][j] - s[1][j] * s[1][j] * inv;
                acc += mz[j] * (cross * cross / (fvar * mvar + 0.1f));
            }
            #pragma unroll
            for (int q = 0; q < 5; ++q) {
                s[q][0] -= lo16(h01[0][q]);
                s[q][1] -= hi16(h01[0][q]);
                s[q][2] -= h2v[0][q];
            }
        }
        #pragma unroll
        for (int a = 0; a < 3; ++a)
            #pragma unroll
            for (int q = 0; q < 5; ++q) { h01[a][q] = h01[a + 1][q]; h2v[a][q] = h2v[a + 1][q]; }
        #pragma unroll
        for (int q = 0; q < 5; ++q) { h01[3][q] = pk(S[q][0], S[q][1]); h2v[3][q] = S[q][2]; }
    }

    // ---- wave reduction; one partial per wave; no LDS, no barrier ----
    #pragma unroll
    for (int off = 32; off > 0; off >>= 1) acc += __shfl_down(acc, off, 64);
    if (lane == 0)
        partials[(blockIdx.y * NXB + blockIdx.x) * WPB + wid] = acc;
}

// ---------------------------------------------------------------------------
// Final deterministic reduction, writes -sum.
// ---------------------------------------------------------------------------
__global__ __launch_bounds__(256) void lcc_finalize(const float* __restrict__ partials,
                                                    int n, float* __restrict__ out) {
    __shared__ float red[256];
    float a = 0.f;
    for (int i = threadIdx.x; i < n; i += 256) a += partials[i];
    red[threadIdx.x] = a;
    __syncthreads();
    #pragma unroll
    for (int st = 128; st > 0; st >>= 1) {
        if (threadIdx.x < st) red[threadIdx.x] += red[threadIdx.x + st];
        __syncthreads();
    }
    if (threadIdx.x == 0) out[0] = -red[0];
}

// ---------------------------------------------------------------------------
// Fallback: direct 125-tap (only if ws is tiny).
// ---------------------------------------------------------------------------
__global__ __launch_bounds__(256) void lcc_direct(const float* __restrict__ f,
                                                  const float* __restrict__ m,
                                                  float* __restrict__ partials) {
    float acc = 0.f;
    for (int idx = blockIdx.x * 256 + threadIdx.x; idx < NVOX; idx += 256 * gridDim.x) {
        const int z = idx % DZ;
        const int y = (idx / DZ) % DY;
        const int x = idx / PLANE;
        float sf = 0, sm = 0, sfm = 0, sff = 0, smm = 0;
        for (int dx = -2; dx <= 2; ++dx) {
            const int xx = iclamp(x + dx, DX - 1);
            for (int dy = -2; dy <= 2; ++dy) {
                const int yy = iclamp(y + dy, DY - 1);
                const size_t b = (size_t)xx * PLANE + (size_t)yy * DZ;
                #pragma unroll
                for (int dz = -2; dz <= 2; ++dz) {
                    const int zz = iclamp(z + dz, DZ - 1);
                    const float fv = f[b + zz], mv = m[b + zz];
                    sf += fv; sm += mv; sfm += fv * mv; sff += fv * fv; smm += mv * mv;
                }
            }
        }
        const float inv = 1.0f / 125.0f;
        const float cross = sfm - sf * sm * inv;
        const float fvar  = sff - sf * sf * inv;
        const float mvar  = smm - sm * sm * inv;
        acc += cross * cross / (fvar * mvar + 0.1f);
    }
    __shared__ float red[256];
    red[threadIdx.x] = acc;
    __syncthreads();
    #pragma unroll
    for (int st = 128; st > 0; st >>= 1) {
        if (threadIdx.x < st) red[threadIdx.x] += red[threadIdx.x + st];
        __syncthreads();
    }
    if (threadIdx.x == 0) partials[blockIdx.x] = red[0];
}

extern "C" void kernel_launch(void* const* d_in, const int* in_sizes, int n_in,
                              void* d_out, int out_size, void* d_ws, size_t ws_size,
                              hipStream_t stream) {
    const float* f = (const float*)d_in[0];
    const float* m = (const float*)d_in[1];
    float* out = (float*)d_out;

    if (ws_size >= NPART * sizeof(float)) {
        float* partials = (float*)d_ws;
        lcc_fused<<<dim3(NXB, NYB), NT, 0, stream>>>(f, m, partials);
        lcc_finalize<<<1, 256, 0, stream>>>(partials, NPART, out);
    } else {
        const int nb = 512;
        float* partials = (float*)d_ws;
        lcc_direct<<<nb, 256, 0, stream>>>(f, m, partials);
        lcc_finalize<<<1, 256, 0, stream>>>(partials, nb, out);
    }
}

// Round 17
// 44.533 us; speedup vs baseline: 1.0493x; 1.0493x over previous
//
#include <hip/hip_runtime.h>
#include <hip/hip_fp16.h>

#define DX 160
#define DY 192
#define DZ 160
#define PLANE (DY*DZ)
#define NVOX (DX*DY*DZ)

#define XC   10               // interior x slices per wave
#define NXB  (DX/XC)          // 16
#define NS   (XC+4)           // 14
#define WPB  4                // waves (= y rows) per block
#define NT   (WPB*64)         // 256 threads
#define NYB  (DY/WPB)         // 48
#define NPART (NXB*NYB*WPB)   // 3072 per-wave partials

__device__ __forceinline__ int iclamp(int v, int hi) {
    return v < 0 ? 0 : (v > hi ? hi : v);
}
__device__ __forceinline__ unsigned pk(float a, float b) {
    return __builtin_bit_cast(unsigned, __floats2half2_rn(a, b));
}
__device__ __forceinline__ float lo16(unsigned u) {
    return __low2float(__builtin_bit_cast(__half2, u));
}
__device__ __forceinline__ float hi16(unsigned u) {
    return __high2float(__builtin_bit_cast(__half2, u));
}

// ---------------------------------------------------------------------------
// Wave-autonomous fused LCC: ZERO LDS, ZERO main-loop barriers.
// R16 post-mortem: concept fine, but allocator targeted 8 waves/EU (64 VGPR)
// against a ~95-reg live set -> 33 MB scratch spill (dispatch-1 WRITE_SIZE).
// Fixes here:
//   1. amdgpu_waves_per_eu(4,4): min=4 caps VGPR at 128, MAX=4 forbids the
//      spill-for-occupancy heuristic that produced 64.
//   2. fp16-pack the S[.][2] history across q-pairs: h2v[4][5] (20 f32) ->
//      h2p[4][3] (12 u32); persistent state ~64 regs, peak ~<128.
// Mapping unchanged: wave = y row; lane owns z-triple 3l..3l+2 (54 lanes
// cover z, masked tail); y-box from global float4 (L1-served), z-box via 2
// fp16 shuffles/quantity, x-box register running window, wave reduction.
// ---------------------------------------------------------------------------
__global__ __launch_bounds__(NT)
__attribute__((amdgpu_waves_per_eu(4, 4)))
void lcc_fused(const float* __restrict__ F,
               const float* __restrict__ M,
               float* __restrict__ partials) {
    const int tid  = threadIdx.x;
    const int lane = tid & 63;
    const int wid  = tid >> 6;
    const int y    = blockIdx.y * WPB + wid;
    const int x0   = blockIdx.x * XC;

    // z-triple base; cap at 156 so the float4 read never leaves the row
    const int  z3   = 3 * lane;
    const int  zoff = z3 < DZ - 4 ? z3 : DZ - 4;   // <=156
    const bool hiL  = (z3 > DZ - 4);               // lanes >= 53: use v.w (z=159)

    // validity masks for the 3 z-slots
    const float mz0 = (z3 + 0 < DZ) ? 1.f : 0.f;
    const float mz1 = (z3 + 1 < DZ) ? 1.f : 0.f;
    const float mz2 = (z3 + 2 < DZ) ? 1.f : 0.f;

    int rowoff[5];
    #pragma unroll
    for (int k = 0; k < 5; ++k)
        rowoff[k] = iclamp(y + k - 2, DY - 1) * DZ + zoff;

    // x running-window state
    float    s[5][3];
    unsigned h01[4][5];   // history: fp16x2 (S[q][0], S[q][1]) per age
    unsigned h2p[4][3];   // history: fp16x2 (S[2q][2], S[2q+1][2]) q-pairs
    #pragma unroll
    for (int q = 0; q < 5; ++q) { s[q][0] = 0.f; s[q][1] = 0.f; s[q][2] = 0.f; }
    #pragma unroll
    for (int a = 0; a < 4; ++a) {
        #pragma unroll
        for (int q = 0; q < 5; ++q) h01[a][q] = 0u;
        #pragma unroll
        for (int p = 0; p < 3; ++p) h2p[a][p] = 0u;
    }

    float acc = 0.f;

    #pragma unroll
    for (int i = 0; i < NS; ++i) {
        const int xx = iclamp(x0 + i - 2, DX - 1);
        const float* fp = F + (size_t)xx * PLANE;
        const float* mp = M + (size_t)xx * PLANE;

        // ---- y-box over 5 tap rows, straight from global (f32 exact) ----
        float q0[5] = {0,0,0,0,0};   // quantities at z-slot 0: f,m,fm,ff,mm
        float q1[5] = {0,0,0,0,0};   // z-slot 1
        float q2[5] = {0,0,0,0,0};   // z-slot 2
        #pragma unroll
        for (int r = 0; r < 5; ++r) {
            const float4 vf = *(const float4*)(fp + rowoff[r]);
            const float4 vm = *(const float4*)(mp + rowoff[r]);
            const float f0 = hiL ? vf.w : vf.x, m0 = hiL ? vm.w : vm.x;
            const float f1 = hiL ? vf.w : vf.y, m1 = hiL ? vm.w : vm.y;
            const float f2 = hiL ? vf.w : vf.z, m2 = hiL ? vm.w : vm.z;
            q0[0] += f0; q0[1] += m0;
            q0[2] = fmaf(f0, m0, q0[2]); q0[3] = fmaf(f0, f0, q0[3]); q0[4] = fmaf(m0, m0, q0[4]);
            q1[0] += f1; q1[1] += m1;
            q1[2] = fmaf(f1, m1, q1[2]); q1[3] = fmaf(f1, f1, q1[3]); q1[4] = fmaf(m1, m1, q1[4]);
            q2[0] += f2; q2[1] += m2;
            q2[2] = fmaf(f2, m2, q2[2]); q2[3] = fmaf(f2, f2, q2[3]); q2[4] = fmaf(m2, m2, q2[4]);
        }

        // ---- z-box via wave-local shuffles (fp16 neighbor taps) ----
        float S[5][3];
        #pragma unroll
        for (int q = 0; q < 5; ++q) {
            const unsigned up = pk(q1[q], q2[q]);   // my (z1,z2) -> right neighbor
            const unsigned dn = pk(q0[q], q1[q]);   // my (z0,z1) -> left neighbor
            unsigned fl = __shfl_up(up, 1, 64);     // lane-1's (z1,z2) = my z0-2, z0-1
            unsigned fr = __shfl_down(dn, 1, 64);   // lane+1's (z0,z1) = my z2+1, z2+2
            if (lane == 0) fl = pk(q0[q], q0[q]);   // replicate pad at z=0
            // (right edge: lanes>=53 duplicated z159 into q1/q2, so lane52's
            //  fr.hi == clamp(z=160) automatically; lane53 uses only S[.][0].)
            const float c = q0[q] + q1[q] + q2[q];
            S[q][0] = c + lo16(fl) + hi16(fl);
            S[q][1] = c + hi16(fl) + lo16(fr);
            S[q][2] = c + lo16(fr) + hi16(fr);
        }

        // ---- x running window + LCC ----
        #pragma unroll
        for (int q = 0; q < 5; ++q) {
            s[q][0] += S[q][0]; s[q][1] += S[q][1]; s[q][2] += S[q][2];
        }
        if (i >= 4) {
            const float inv = 1.0f / 125.0f;
            const float mz[3] = {mz0, mz1, mz2};
            #pragma unroll
            for (int j = 0; j < 3; ++j) {
                const float cross = s[2][j] - s[0][j] * s[1][j] * inv;
                const float fvar  = s[3][j] - s[0][j] * s[0][j] * inv;
                const float mvar  = s[4][j] - s[1][j] * s[1][j] * inv;
                acc += mz[j] * (cross * cross / (fvar * mvar + 0.1f));
            }
            #pragma unroll
            for (int q = 0; q < 5; ++q) {
                s[q][0] -= lo16(h01[0][q]);
                s[q][1] -= hi16(h01[0][q]);
            }
            s[0][2] -= lo16(h2p[0][0]);
            s[1][2] -= hi16(h2p[0][0]);
            s[2][2] -= lo16(h2p[0][1]);
            s[3][2] -= hi16(h2p[0][1]);
            s[4][2] -= lo16(h2p[0][2]);
        }
        #pragma unroll
        for (int a = 0; a < 3; ++a) {
            #pragma unroll
            for (int q = 0; q < 5; ++q) h01[a][q] = h01[a + 1][q];
            #pragma unroll
            for (int p = 0; p < 3; ++p) h2p[a][p] = h2p[a + 1][p];
        }
        #pragma unroll
        for (int q = 0; q < 5; ++q) h01[3][q] = pk(S[q][0], S[q][1]);
        h2p[3][0] = pk(S[0][2], S[1][2]);
        h2p[3][1] = pk(S[2][2], S[3][2]);
        h2p[3][2] = pk(S[4][2], 0.f);
    }

    // ---- wave reduction; one partial per wave; no LDS, no barrier ----
    #pragma unroll
    for (int off = 32; off > 0; off >>= 1) acc += __shfl_down(acc, off, 64);
    if (lane == 0)
        partials[(blockIdx.y * NXB + blockIdx.x) * WPB + wid] = acc;
}

// ---------------------------------------------------------------------------
// Final deterministic reduction, writes -sum.
// ---------------------------------------------------------------------------
__global__ __launch_bounds__(256) void lcc_finalize(const float* __restrict__ partials,
                                                    int n, float* __restrict__ out) {
    __shared__ float red[256];
    float a = 0.f;
    for (int i = threadIdx.x; i < n; i += 256) a += partials[i];
    red[threadIdx.x] = a;
    __syncthreads();
    #pragma unroll
    for (int st = 128; st > 0; st >>= 1) {
        if (threadIdx.x < st) red[threadIdx.x] += red[threadIdx.x + st];
        __syncthreads();
    }
    if (threadIdx.x == 0) out[0] = -red[0];
}

// ---------------------------------------------------------------------------
// Fallback: direct 125-tap (only if ws is tiny).
// ---------------------------------------------------------------------------
__global__ __launch_bounds__(256) void lcc_direct(const float* __restrict__ f,
                                                  const float* __restrict__ m,
                                                  float* __restrict__ partials) {
    float acc = 0.f;
    for (int idx = blockIdx.x * 256 + threadIdx.x; idx < NVOX; idx += 256 * gridDim.x) {
        const int z = idx % DZ;
        const int y = (idx / DZ) % DY;
        const int x = idx / PLANE;
        float sf = 0, sm = 0, sfm = 0, sff = 0, smm = 0;
        for (int dx = -2; dx <= 2; ++dx) {
            const int xx = iclamp(x + dx, DX - 1);
            for (int dy = -2; dy <= 2; ++dy) {
                const int yy = iclamp(y + dy, DY - 1);
                const size_t b = (size_t)xx * PLANE + (size_t)yy * DZ;
                #pragma unroll
                for (int dz = -2; dz <= 2; ++dz) {
                    const int zz = iclamp(z + dz, DZ - 1);
                    const float fv = f[b + zz], mv = m[b + zz];
                    sf += fv; sm += mv; sfm += fv * mv; sff += fv * fv; smm += mv * mv;
                }
            }
        }
        const float inv = 1.0f / 125.0f;
        const float cross = sfm - sf * sm * inv;
        const float fvar  = sff - sf * sf * inv;
        const float mvar  = smm - sm * sm * inv;
        acc += cross * cross / (fvar * mvar + 0.1f);
    }
    __shared__ float red[256];
    red[threadIdx.x] = acc;
    __syncthreads();
    #pragma unroll
    for (int st = 128; st > 0; st >>= 1) {
        if (threadIdx.x < st) red[threadIdx.x] += red[threadIdx.x + st];
        __syncthreads();
    }
    if (threadIdx.x == 0) partials[blockIdx.x] = red[0];
}

extern "C" void kernel_launch(void* const* d_in, const int* in_sizes, int n_in,
                              void* d_out, int out_size, void* d_ws, size_t ws_size,
                              hipStream_t stream) {
    const float* f = (const float*)d_in[0];
    const float* m = (const float*)d_in[1];
    float* out = (float*)d_out;

    if (ws_size >= NPART * sizeof(float)) {
        float* partials = (float*)d_ws;
        lcc_fused<<<dim3(NXB, NYB), NT, 0, stream>>>(f, m, partials);
        lcc_finalize<<<1, 256, 0, stream>>>(partials, NPART, out);
    } else {
        const int nb = 512;
        float* partials = (float*)d_ws;
        lcc_direct<<<nb, 256, 0, stream>>>(f, m, partials);
        lcc_finalize<<<1, 256, 0, stream>>>(partials, nb, out);
    }
}

// Round 18
// 38.227 us; speedup vs baseline: 1.2224x; 1.1650x over previous
//
#include <hip/hip_runtime.h>
#include <hip/hip_fp16.h>

#define DX 160
#define DY 192
#define DZ 160
#define PLANE (DY*DZ)
#define NVOX (DX*DY*DZ)

#define XC   20              // interior x slices per wave
#define NXB  (DX/XC)         // 8
#define NS   (XC+4)          // 24
#define WPB  4               // waves per block (4 consecutive y, same seg)
#define NT   (WPB*64)        // 256 threads
#define NSEG 3               // z segments: zbase = 60*seg - 2, 60 outputs each
#define NTASK (DY*NSEG)      // 576 wave-tasks
#define NBY  (NTASK/WPB)     // 144
#define NPART (NXB*NBY*WPB)  // 4608

__device__ __forceinline__ int iclamp(int v, int hi) {
    return v < 0 ? 0 : (v > hi ? hi : v);
}
__device__ __forceinline__ unsigned pk(float a, float b) {
    return __builtin_bit_cast(unsigned, __floats2half2_rn(a, b));
}
__device__ __forceinline__ __half2 h2(unsigned v) {
    return __builtin_bit_cast(__half2, v);
}
__device__ __forceinline__ float lo16(unsigned u) { return __low2float(h2(u)); }
__device__ __forceinline__ float hi16(unsigned u) { return __high2float(h2(u)); }

// ---------------------------------------------------------------------------
// Wave-autonomous fused LCC, 64-VGPR edition.
// R16/R17: the ~95-reg z-triple variant spilled 30 MB because the allocator
// gives 256-thread kernels 64 VGPRs regardless of launch_bounds /
// amdgpu_waves_per_eu (VGPR_Count=64 both rounds). So: FIT 64.
//   - lane owns ONE z; wave = 64 consecutive z of one y row with 2-lane halo
//     each side -> 60 interior outputs; 3 segments (zbase=60*seg-2) cover 160.
//   - clamped loads = replicate padding at true z edges, free; interior
//     segment halos are real neighbor values; lanes 0,1,62,63 are halo-only
//     (feed shuffles, masked out of acc).
//   - z-box: 4 shuffles x 3 fp16-packed words; y-box: 5 clamped rows direct
//     from global (block = 4 consecutive y, same seg -> L1 serves 4/5 of
//     tap redundancy); x-box: register running window, fp16 history.
//   - live set ~55 VGPR; zero LDS; zero barriers.
// ---------------------------------------------------------------------------
__global__ __launch_bounds__(NT) void lcc_fused(const float* __restrict__ F,
                                                const float* __restrict__ M,
                                                float* __restrict__ partials) {
    const int tid  = threadIdx.x;
    const int lane = tid & 63;
    const int wid  = tid >> 6;
    const int task = blockIdx.y * WPB + wid;   // seg-major: 4 consecutive y/block
    const int seg  = task / DY;
    const int y    = task % DY;
    const int x0   = blockIdx.x * XC;
    const int z    = seg * 60 - 2 + lane;      // may be <0 or >=DZ (halo lanes)
    const int zl   = iclamp(z, DZ - 1);
    const float valid = (lane >= 2 && lane <= 61 && z < DZ) ? 1.f : 0.f;

    int rowoff[5];
    #pragma unroll
    for (int k = 0; k < 5; ++k)
        rowoff[k] = iclamp(y + k - 2, DY - 1) * DZ + zl;

    // x running-window state (scalar per lane)
    float s0 = 0.f, s1 = 0.f, s2 = 0.f, s3 = 0.f, s4 = 0.f;
    unsigned hA[4], hB[4], hC[4];   // fp16x2 history: (S0,S1),(S2,S3),(S4,-)
    #pragma unroll
    for (int a = 0; a < 4; ++a) { hA[a] = 0u; hB[a] = 0u; hC[a] = 0u; }
    float acc = 0.f;

    for (int i = 0; i < NS; ++i) {
        const int xx = iclamp(x0 + i - 2, DX - 1);
        const float* fp = F + (size_t)xx * PLANE;
        const float* mp = M + (size_t)xx * PLANE;

        // ---- y-box: 5 clamped rows straight from global (f32 exact) ----
        float q0 = 0.f, q1 = 0.f, q2 = 0.f, q3 = 0.f, q4 = 0.f;
        #pragma unroll
        for (int r = 0; r < 5; ++r) {
            const float fv = fp[rowoff[r]];
            const float mv = mp[rowoff[r]];
            q0 += fv; q1 += mv;
            q2 = fmaf(fv, mv, q2);
            q3 = fmaf(fv, fv, q3);
            q4 = fmaf(mv, mv, q4);
        }

        // ---- z-box via wave shuffles (taps z-2..z+2 in lanes l-2..l+2) ----
        const unsigned P01 = pk(q0, q1);
        const unsigned P23 = pk(q2, q3);
        const unsigned P4  = pk(q4, q4);
        const __half2 t01 = __hadd2(
            __hadd2(h2(__shfl_up(P01, 1, 64)), h2(__shfl_up(P01, 2, 64))),
            __hadd2(h2(__shfl_down(P01, 1, 64)), h2(__shfl_down(P01, 2, 64))));
        const __half2 t23 = __hadd2(
            __hadd2(h2(__shfl_up(P23, 1, 64)), h2(__shfl_up(P23, 2, 64))),
            __hadd2(h2(__shfl_down(P23, 1, 64)), h2(__shfl_down(P23, 2, 64))));
        const __half2 t4 = __hadd2(
            __hadd2(h2(__shfl_up(P4, 1, 64)), h2(__shfl_up(P4, 2, 64))),
            __hadd2(h2(__shfl_down(P4, 1, 64)), h2(__shfl_down(P4, 2, 64))));
        const float S0 = q0 + __low2float(t01);
        const float S1 = q1 + __high2float(t01);
        const float S2 = q2 + __low2float(t23);
        const float S3 = q3 + __high2float(t23);
        const float S4 = q4 + __low2float(t4);

        // ---- x running window + LCC ----
        s0 += S0; s1 += S1; s2 += S2; s3 += S3; s4 += S4;
        if (i >= 4) {
            const float inv = 1.0f / 125.0f;
            const float cross = s2 - s0 * s1 * inv;
            const float fvar  = s3 - s0 * s0 * inv;
            const float mvar  = s4 - s1 * s1 * inv;
            acc += valid * (cross * cross / (fvar * mvar + 0.1f));
            s0 -= lo16(hA[0]); s1 -= hi16(hA[0]);
            s2 -= lo16(hB[0]); s3 -= hi16(hB[0]);
            s4 -= lo16(hC[0]);
        }
        hA[0] = hA[1]; hA[1] = hA[2]; hA[2] = hA[3]; hA[3] = pk(S0, S1);
        hB[0] = hB[1]; hB[1] = hB[2]; hB[2] = hB[3]; hB[3] = pk(S2, S3);
        hC[0] = hC[1]; hC[1] = hC[2]; hC[2] = hC[3]; hC[3] = pk(S4, 0.f);
    }

    // ---- wave reduction; one partial per wave; no LDS, no barrier ----
    #pragma unroll
    for (int off = 32; off > 0; off >>= 1) acc += __shfl_down(acc, off, 64);
    if (lane == 0)
        partials[(blockIdx.y * NXB + blockIdx.x) * WPB + wid] = acc;
}

// ---------------------------------------------------------------------------
// Final deterministic reduction, writes -sum.
// ---------------------------------------------------------------------------
__global__ __launch_bounds__(256) void lcc_finalize(const float* __restrict__ partials,
                                                    int n, float* __restrict__ out) {
    __shared__ float red[256];
    float a = 0.f;
    for (int i = threadIdx.x; i < n; i += 256) a += partials[i];
    red[threadIdx.x] = a;
    __syncthreads();
    #pragma unroll
    for (int st = 128; st > 0; st >>= 1) {
        if (threadIdx.x < st) red[threadIdx.x] += red[threadIdx.x + st];
        __syncthreads();
    }
    if (threadIdx.x == 0) out[0] = -red[0];
}

// ---------------------------------------------------------------------------
// Fallback: direct 125-tap (only if ws is tiny).
// ---------------------------------------------------------------------------
__global__ __launch_bounds__(256) void lcc_direct(const float* __restrict__ f,
                                                  const float* __restrict__ m,
                                                  float* __restrict__ partials) {
    float acc = 0.f;
    for (int idx = blockIdx.x * 256 + threadIdx.x; idx < NVOX; idx += 256 * gridDim.x) {
        const int z = idx % DZ;
        const int y = (idx / DZ) % DY;
        const int x = idx / PLANE;
        float sf = 0, sm = 0, sfm = 0, sff = 0, smm = 0;
        for (int dx = -2; dx <= 2; ++dx) {
            const int xx = iclamp(x + dx, DX - 1);
            for (int dy = -2; dy <= 2; ++dy) {
                const int yy = iclamp(y + dy, DY - 1);
                const size_t b = (size_t)xx * PLANE + (size_t)yy * DZ;
                #pragma unroll
                for (int dz = -2; dz <= 2; ++dz) {
                    const int zz = iclamp(z + dz, DZ - 1);
                    const float fv = f[b + zz], mv = m[b + zz];
                    sf += fv; sm += mv; sfm += fv * mv; sff += fv * fv; smm += mv * mv;
                }
            }
        }
        const float inv = 1.0f / 125.0f;
        const float cross = sfm - sf * sm * inv;
        const float fvar  = sff - sf * sf * inv;
        const float mvar  = smm - sm * sm * inv;
        acc += cross * cross / (fvar * mvar + 0.1f);
    }
    __shared__ float red[256];
    red[threadIdx.x] = acc;
    __syncthreads();
    #pragma unroll
    for (int st = 128; st > 0; st >>= 1) {
        if (threadIdx.x < st) red[threadIdx.x] += red[threadIdx.x + st];
        __syncthreads();
    }
    if (threadIdx.x == 0) partials[blockIdx.x] = red[0];
}

extern "C" void kernel_launch(void* const* d_in, const int* in_sizes, int n_in,
                              void* d_out, int out_size, void* d_ws, size_t ws_size,
                              hipStream_t stream) {
    const float* f = (const float*)d_in[0];
    const float* m = (const float*)d_in[1];
    float* out = (float*)d_out;

    if (ws_size >= NPART * sizeof(float)) {
        float* partials = (float*)d_ws;
        lcc_fused<<<dim3(NXB, NBY), NT, 0, stream>>>(f, m, partials);
        lcc_finalize<<<1, 256, 0, stream>>>(partials, NPART, out);
    } else {
        const int nb = 512;
        float* partials = (float*)d_ws;
        lcc_direct<<<nb, 256, 0, stream>>>(f, m, partials);
        lcc_finalize<<<1, 256, 0, stream>>>(partials, nb, out);
    }
}